// Round 4
// baseline (103.496 us; speedup 1.0000x reference)
//
#include <hip/hip_runtime.h>
#include <hip/hip_bf16.h>
#include <cmath>

typedef unsigned short u16;
typedef __bf16 bf16x8 __attribute__((ext_vector_type(8)));
typedef float  f32x4  __attribute__((ext_vector_type(4)));
typedef float  f4     __attribute__((ext_vector_type(4)));
typedef u16    us4    __attribute__((ext_vector_type(4)));

#define DEVFN __device__ __forceinline__

static constexpr int Bq = 2, Nq = 2048, Eq = 1024;
static constexpr int Mq = Bq * Nq;        // 4096 tokens
static constexpr int CHK = 64;            // attention chunk
static constexpr int NC  = Nq / CHK;      // 32 chunks
static constexpr int BH  = Bq * 16;       // 32

DEVFN u16 f2b(float f) {                  // f32 -> bf16 (RNE), finite inputs
    union { float f; unsigned int u; } x; x.f = f;
    unsigned int r = x.u + 0x7fffu + ((x.u >> 16) & 1u);
    return (u16)(r >> 16);
}

DEVFN void gl_lds16(const u16* g, u16* l) {  // async 16B global->LDS (dest: wave base + lane*16)
    __builtin_amdgcn_global_load_lds(
        (const __attribute__((address_space(1))) unsigned int*)(g),
        (__attribute__((address_space(3))) unsigned int*)(l),
        16, 0, 0);
}

// ---------------- f32 -> bf16 bulk converts ----------------
__global__ __launch_bounds__(256) void cvt_kernel(const float* __restrict__ src,
                                                  u16* __restrict__ dst, int n4) {
    int i = blockIdx.x * 256 + threadIdx.x;
    if (i < n4) {
        f4 v = *reinterpret_cast<const f4*>(&src[(size_t)i * 4]);
        us4 p; p[0] = f2b(v[0]); p[1] = f2b(v[1]); p[2] = f2b(v[2]); p[3] = f2b(v[3]);
        *reinterpret_cast<us4*>(&dst[(size_t)i * 4]) = p;
    }
}

__global__ __launch_bounds__(256) void cvt4_kernel(const float* __restrict__ s0,
                                                   const float* __restrict__ s1,
                                                   const float* __restrict__ s2,
                                                   const float* __restrict__ s3,
                                                   u16* __restrict__ dst, int n4each) {
    const int which = blockIdx.y;
    const float* s = (which == 0) ? s0 : (which == 1) ? s1 : (which == 2) ? s2 : s3;
    int i = blockIdx.x * 256 + threadIdx.x;
    if (i < n4each) {
        f4 v = *reinterpret_cast<const f4*>(&s[(size_t)i * 4]);
        us4 p; p[0] = f2b(v[0]); p[1] = f2b(v[1]); p[2] = f2b(v[2]); p[3] = f2b(v[3]);
        *reinterpret_cast<us4*>(&dst[((size_t)which * n4each + i) * 4]) = p;
    }
}

// ============ QKV: 256x256 tile, 8 waves, BK=32, 4-buffer LDS ring, phased ============
// out[m][n] = act(X[m][:] . W[n][:] + bias), N=3072 (seg 0=Q elu+1, 1=K elu+1, 2=V)
// Schedule per K-tile t (buffer t&3): 2 phases x {ds_read frags; stage 2 rounds of
// K-tile t+2 into buf[(t+2)&3]; s_barrier; setprio(1); 16 MFMA; setprio(0); s_barrier}.
// End of t: s_waitcnt vmcnt(4) (K_{t+1} landed, K_{t+2}'s 4 loads still in flight).
__global__ __launch_bounds__(512, 2)
void qkv_kernel(const u16* __restrict__ X, const u16* __restrict__ W,
                const float* __restrict__ b0, const float* __restrict__ b1,
                const float* __restrict__ b2,
                u16* __restrict__ Qb, u16* __restrict__ Kb, u16* __restrict__ KbT,
                u16* __restrict__ VbT)
{
    __shared__ u16 lds[4 * 16384];               // 4 ring buffers x 32KB (A 16KB | B 16KB)
    const int tid  = threadIdx.x;
    const int m0   = blockIdx.y * 256, n0 = blockIdx.x * 256;
    const int wid  = tid >> 6, lane = tid & 63;
    const int wr   = (wid >> 2) * 128;           // 2 M-halves of waves
    const int wc   = (wid & 3) * 64;             // 4 N-quarters
    const int fr   = lane & 15, fq = lane >> 4;

    // --- staging addressing: round r of K-tile kt: r&1 = row-half, r>>1 = A/B part
    const int srow  = tid >> 2;                  // 0..127
    const int scol8 = ((tid & 3) ^ (srow & 3)) * 8;   // inverse-swizzled global 16B slot
    const u16* gX = X + (size_t)(m0 + srow) * 1024 + scol8;
    const u16* gW = W + (size_t)(n0 + srow) * 1024 + scol8;
    const int dbase = srow * 32 + (tid & 3) * 8; // linear LDS dest (u16)

    // --- fragment read offsets (u16), swizzled read side (same involution)
    const int fsw = ((fq ^ (fr & 3)) << 3);
    int aoff[2][4], boff[4];
#pragma unroll
    for (int mh = 0; mh < 2; ++mh)
#pragma unroll
        for (int mi = 0; mi < 4; ++mi)
            aoff[mh][mi] = (wr + mh * 64 + mi * 16 + fr) * 32 + fsw;
#pragma unroll
    for (int ni = 0; ni < 4; ++ni)
        boff[ni] = 8192 + (wc + ni * 16 + fr) * 32 + fsw;

#define STAGE(kt, r) do {                                                          \
        const u16* _s = (((r) >> 1) ? gW : gX) + (size_t)((r)&1) * 131072 + (kt) * 32; \
        u16* _d = lds + ((kt)&3) * 16384 + ((r) >> 1) * 8192 + ((r)&1) * 4096 + dbase; \
        gl_lds16(_s, _d);                                                          \
    } while (0)

    // prologue: K0 + K1 fully staged; wait K0 (4 newest = K1 still in flight)
#pragma unroll
    for (int r = 0; r < 4; ++r) STAGE(0, r);
#pragma unroll
    for (int r = 0; r < 4; ++r) STAGE(1, r);
    asm volatile("s_waitcnt vmcnt(4)" ::: "memory");
    __builtin_amdgcn_sched_barrier(0);
    __builtin_amdgcn_s_barrier();

    f32x4 acc[8][4] = {};

    for (int t = 0; t < 32; ++t) {
        const u16* buf = lds + (t & 3) * 16384;
        bf16x8 a[4], b[4];
        // ---------- phase 0 (rows wr..wr+63) ----------
#pragma unroll
        for (int ni = 0; ni < 4; ++ni)
            b[ni] = *reinterpret_cast<const bf16x8*>(&buf[boff[ni]]);
#pragma unroll
        for (int mi = 0; mi < 4; ++mi)
            a[mi] = *reinterpret_cast<const bf16x8*>(&buf[aoff[0][mi]]);
        if (t + 2 < 32) { STAGE(t + 2, 0); STAGE(t + 2, 1); }
        __builtin_amdgcn_s_barrier();
        __builtin_amdgcn_s_setprio(1);
#pragma unroll
        for (int mi = 0; mi < 4; ++mi)
#pragma unroll
            for (int ni = 0; ni < 4; ++ni)
                acc[mi][ni] = __builtin_amdgcn_mfma_f32_16x16x32_bf16(
                    a[mi], b[ni], acc[mi][ni], 0, 0, 0);
        __builtin_amdgcn_s_setprio(0);
        __builtin_amdgcn_s_barrier();
        // ---------- phase 1 (rows wr+64..wr+127) ----------
#pragma unroll
        for (int mi = 0; mi < 4; ++mi)
            a[mi] = *reinterpret_cast<const bf16x8*>(&buf[aoff[1][mi]]);
        if (t + 2 < 32) { STAGE(t + 2, 2); STAGE(t + 2, 3); }
        __builtin_amdgcn_s_barrier();
        __builtin_amdgcn_s_setprio(1);
#pragma unroll
        for (int mi = 0; mi < 4; ++mi)
#pragma unroll
            for (int ni = 0; ni < 4; ++ni)
                acc[4 + mi][ni] = __builtin_amdgcn_mfma_f32_16x16x32_bf16(
                    a[mi], b[ni], acc[4 + mi][ni], 0, 0, 0);
        __builtin_amdgcn_s_setprio(0);
        // K-tile boundary: ensure K_{t+1} landed; keep K_{t+2}'s 4 loads in flight
        if (t < 30)       asm volatile("s_waitcnt vmcnt(4)" ::: "memory");
        else if (t == 30) asm volatile("s_waitcnt vmcnt(0)" ::: "memory");
        __builtin_amdgcn_sched_barrier(0);
        __builtin_amdgcn_s_barrier();
    }
#undef STAGE

    // ---------- epilogue ----------
    const int seg = n0 >> 10;                          // 0=q 1=k 2=v (256 | 1024)
    const float* bp = (seg == 0) ? b0 : (seg == 1) ? b1 : b2;
#pragma unroll
    for (int mg = 0; mg < 8; ++mg)
#pragma unroll
        for (int ni = 0; ni < 4; ++ni) {
            const int nl    = (n0 & 1023) + wc + ni * 16 + fr;
            const int mbase = m0 + wr + mg * 16 + fq * 4;
            const float bn  = bp[nl];
            float vr[4];
#pragma unroll
            for (int r = 0; r < 4; ++r) {
                float v = acc[mg][ni][r] + bn;
                if (seg < 2) v = (v > 0.f) ? (v + 1.f) : __expf(v);  // elu+1
                vr[r] = v;
            }
            if (seg == 0) {
#pragma unroll
                for (int r = 0; r < 4; ++r)
                    Qb[(size_t)(mbase + r) * 1024 + nl] = f2b(vr[r]);
            } else {
                us4 pk;
#pragma unroll
                for (int r = 0; r < 4; ++r) pk[r] = f2b(vr[r]);
                const int bb = mbase >> 11, nt = mbase & 2047;
                const int hh = nl >> 6,     dd = nl & 63;
                u16* T = (seg == 1) ? KbT : VbT;
                *reinterpret_cast<us4*>(
                    &T[((size_t)(bb * 16 + hh) * 64 + dd) * 2048 + nt]) = pk;
                if (seg == 1) {
#pragma unroll
                    for (int r = 0; r < 4; ++r)
                        Kb[(size_t)(mbase + r) * 1024 + nl] = f2b(vr[r]);
                }
            }
        }
}

// ---------------- O-proj GEMM (R3 structure, BM=64, BK=64, both-sides swizzle) ----------------
DEVFN const bf16x8* frag(const u16* S, int R, int G) {
    return reinterpret_cast<const bf16x8*>(&S[R * 64 + ((G ^ (R & 7)) << 3)]);
}

__global__ __launch_bounds__(256)
void oproj_kernel(const u16* __restrict__ X, const u16* __restrict__ W,
                  const float* __restrict__ b0, float* __restrict__ outF)
{
    constexpr int BM = 64;
    constexpr int MI = BM / 32;
    __shared__ u16 As[BM * 64];
    __shared__ u16 Bs[128 * 64];
    const int tid  = threadIdx.x;
    const int m0   = blockIdx.y * BM, n0 = blockIdx.x * 128;
    const int wid  = tid >> 6, lane = tid & 63;
    const int wr   = (wid >> 1) * (BM / 2), wc = (wid & 1) * 64;
    const int fr   = lane & 15, fq = lane >> 4;

    const int srow = tid >> 3;
    const int sw   = (tid & 7) ^ (srow & 7);
    const u16* gA = X + (size_t)(m0 + srow) * 1024 + sw * 8;
    const u16* gB = W + (size_t)(n0 + srow) * 1024 + sw * 8;
    u16* lA = As + wid * 512;
    u16* lB = Bs + wid * 512;

    f32x4 acc[MI][4] = {};

    for (int k0 = 0; k0 < 1024; k0 += 64) {
        __syncthreads();
#pragma unroll
        for (int i = 0; i < BM / 32; ++i)
            gl_lds16(gA + k0 + i * 32 * 1024, lA + i * 2048);
#pragma unroll
        for (int i = 0; i < 4; ++i)
            gl_lds16(gB + k0 + i * 32 * 1024, lB + i * 2048);
        __syncthreads();

#pragma unroll
        for (int kk = 0; kk < 2; ++kk) {
            bf16x8 af[MI], bfv[4];
#pragma unroll
            for (int mi = 0; mi < MI; ++mi)
                af[mi] = *frag(As, wr + mi * 16 + fr, kk * 4 + fq);
#pragma unroll
            for (int ni = 0; ni < 4; ++ni)
                bfv[ni] = *frag(Bs, wc + ni * 16 + fr, kk * 4 + fq);
#pragma unroll
            for (int mi = 0; mi < MI; ++mi)
#pragma unroll
                for (int ni = 0; ni < 4; ++ni)
                    acc[mi][ni] = __builtin_amdgcn_mfma_f32_16x16x32_bf16(
                        af[mi], bfv[ni], acc[mi][ni], 0, 0, 0);
        }
    }

#pragma unroll
    for (int mi = 0; mi < MI; ++mi)
#pragma unroll
        for (int ni = 0; ni < 4; ++ni) {
            const int n     = n0 + wc + ni * 16 + fr;
            const int mbase = m0 + wr + mi * 16 + fq * 4;
            const float bn  = b0[n];
#pragma unroll
            for (int r = 0; r < 4; ++r)
                outF[(size_t)(mbase + r) * 1024 + n] = acc[mi][ni][r] + bn;
        }
}

// ---------------- per-chunk KV^T = v_chunk^T @ k_chunk: KVT[de][dk] ----------------
__global__ __launch_bounds__(64)
void chunk_kv_kernel(const u16* __restrict__ KbT, const u16* __restrict__ VbT,
                     float* __restrict__ KVT)
{
    const int blk = blockIdx.x;          // bh*NC + c
    const int bh = blk >> 5, c = blk & 31;
    const int lane = threadIdx.x;
    const int fr = lane & 15, fq = lane >> 4, fk = fq * 8;
    const u16* kt = KbT + (size_t)bh * 64 * 2048;
    const u16* vt = VbT + (size_t)bh * 64 * 2048;

    bf16x8 a[4][2], b[4][2];             // a = V rows (de), b = K rows (dk)
#pragma unroll
    for (int mi = 0; mi < 4; ++mi)
#pragma unroll
        for (int kh = 0; kh < 2; ++kh)
            a[mi][kh] = *reinterpret_cast<const bf16x8*>(
                &vt[(size_t)(mi * 16 + fr) * 2048 + c * 64 + kh * 32 + fk]);
#pragma unroll
    for (int ni = 0; ni < 4; ++ni)
#pragma unroll
        for (int kh = 0; kh < 2; ++kh)
            b[ni][kh] = *reinterpret_cast<const bf16x8*>(
                &kt[(size_t)(ni * 16 + fr) * 2048 + c * 64 + kh * 32 + fk]);

    f32x4 acc[4][4] = {};
#pragma unroll
    for (int mi = 0; mi < 4; ++mi)
#pragma unroll
        for (int ni = 0; ni < 4; ++ni)
#pragma unroll
            for (int kh = 0; kh < 2; ++kh)
                acc[mi][ni] = __builtin_amdgcn_mfma_f32_16x16x32_bf16(
                    a[mi][kh], b[ni][kh], acc[mi][ni], 0, 0, 0);

    float* out = KVT + (size_t)blk * 4096;   // [de][dk]
#pragma unroll
    for (int mi = 0; mi < 4; ++mi)
#pragma unroll
        for (int ni = 0; ni < 4; ++ni)
#pragma unroll
            for (int r = 0; r < 4; ++r)
                out[(mi * 16 + fq * 4 + r) * 64 + ni * 16 + fr] = acc[mi][ni][r];
}

// ---------------- elementwise exclusive scan over chunks ----------------
__global__ __launch_bounds__(256)
void scan_kernel(const float* __restrict__ KVT, u16* __restrict__ STb)
{
    const int bh = blockIdx.x >> 4, sl = blockIdx.x & 15;
    const int el = sl * 256 + threadIdx.x;              // element of [de][dk]
    const float* src = KVT + (size_t)bh * NC * 4096 + el;
    u16*         dst = STb + (size_t)bh * NC * 4096 + el;
    float run = 0.f;
#pragma unroll 4
    for (int c = 0; c < NC; ++c) {
        dst[(size_t)c * 4096] = f2b(run);               // exclusive prefix
        run += src[(size_t)c * 4096];
    }
}

// ---------------- per-chunk attention output ----------------
__global__ __launch_bounds__(64)
void attn_kernel(const u16* __restrict__ Qb, const u16* __restrict__ Kb,
                 const u16* __restrict__ VbT, const u16* __restrict__ STb,
                 u16* __restrict__ Ob)
{
    __shared__ u16 P[64 * 72];   // stride 72 u16 = 144B: 16B-aligned, 2-way banks
    const int blk = blockIdx.x;
    const int bh = blk >> 5, c = blk & 31;
    const int b = bh >> 4, h = bh & 15;
    const int lane = threadIdx.x;
    const int fr = lane & 15, fq = lane >> 4, fk = fq * 8;
    const int tok0 = b * 2048 + c * 64;

    bf16x8 qa[4][2];
#pragma unroll
    for (int mi = 0; mi < 4; ++mi)
#pragma unroll
        for (int kh = 0; kh < 2; ++kh)
            qa[mi][kh] = *reinterpret_cast<const bf16x8*>(
                &Qb[(size_t)(tok0 + mi * 16 + fr) * 1024 + h * 64 + kh * 32 + fk]);

    // P = causal-mask(q @ k^T) -> LDS bf16
    {
        bf16x8 kb[4][2];
#pragma unroll
        for (int si = 0; si < 4; ++si)
#pragma unroll
            for (int kh = 0; kh < 2; ++kh)
                kb[si][kh] = *reinterpret_cast<const bf16x8*>(
                    &Kb[(size_t)(tok0 + si * 16 + fr) * 1024 + h * 64 + kh * 32 + fk]);
        f32x4 p[4][4] = {};
#pragma unroll
        for (int mi = 0; mi < 4; ++mi)
#pragma unroll
            for (int si = 0; si < 4; ++si)
#pragma unroll
                for (int kh = 0; kh < 2; ++kh)
                    p[mi][si] = __builtin_amdgcn_mfma_f32_16x16x32_bf16(
                        qa[mi][kh], kb[si][kh], p[mi][si], 0, 0, 0);
#pragma unroll
        for (int mi = 0; mi < 4; ++mi)
#pragma unroll
            for (int si = 0; si < 4; ++si)
#pragma unroll
                for (int r = 0; r < 4; ++r) {
                    int t = mi * 16 + fq * 4 + r;
                    int s = si * 16 + fr;
                    float v = (s <= t) ? p[mi][si][r] : 0.0f;
                    P[t * 72 + s] = f2b(v);
                }
    }
    __syncthreads();

    f32x4 acc[4][4] = {};
    // acc = q @ ST   (STb[de][dk], dk-contiguous)
    {
        const u16* st = STb + (size_t)blk * 4096;
        bf16x8 sb[4][2];
#pragma unroll
        for (int ni = 0; ni < 4; ++ni)
#pragma unroll
            for (int kh = 0; kh < 2; ++kh)
                sb[ni][kh] = *reinterpret_cast<const bf16x8*>(
                    &st[(ni * 16 + fr) * 64 + kh * 32 + fk]);
#pragma unroll
        for (int mi = 0; mi < 4; ++mi)
#pragma unroll
            for (int ni = 0; ni < 4; ++ni)
#pragma unroll
                for (int kh = 0; kh < 2; ++kh)
                    acc[mi][ni] = __builtin_amdgcn_mfma_f32_16x16x32_bf16(
                        qa[mi][kh], sb[ni][kh], acc[mi][ni], 0, 0, 0);
    }
    // acc += P @ v
    {
        const u16* vt = VbT + (size_t)bh * 64 * 2048;
#pragma unroll
        for (int sh = 0; sh < 2; ++sh) {
            bf16x8 pa[4], vb[4];
#pragma unroll
            for (int mi = 0; mi < 4; ++mi)
                pa[mi] = *reinterpret_cast<const bf16x8*>(
                    &P[(mi * 16 + fr) * 72 + sh * 32 + fk]);
#pragma unroll
            for (int ni = 0; ni < 4; ++ni)
                vb[ni] = *reinterpret_cast<const bf16x8*>(
                    &vt[(size_t)(ni * 16 + fr) * 2048 + c * 64 + sh * 32 + fk]);
#pragma unroll
            for (int mi = 0; mi < 4; ++mi)
#pragma unroll
                for (int ni = 0; ni < 4; ++ni)
                    acc[mi][ni] = __builtin_amdgcn_mfma_f32_16x16x32_bf16(
                        pa[mi], vb[ni], acc[mi][ni], 0, 0, 0);
        }
    }
    // write token-major bf16 O
#pragma unroll
    for (int mi = 0; mi < 4; ++mi)
#pragma unroll
        for (int ni = 0; ni < 4; ++ni)
#pragma unroll
            for (int r = 0; r < 4; ++r) {
                int t = tok0 + mi * 16 + fq * 4 + r;
                int n = h * 64 + ni * 16 + fr;
                Ob[(size_t)t * 1024 + n] = f2b(acc[mi][ni][r]);
            }
}

extern "C" void kernel_launch(void* const* d_in, const int* in_sizes, int n_in,
                              void* d_out, int out_size, void* d_ws, size_t ws_size,
                              hipStream_t stream)
{
    (void)in_sizes; (void)n_in; (void)out_size; (void)ws_size;
    const float* x  = (const float*)d_in[0];
    const float* Wq = (const float*)d_in[1];
    const float* bq = (const float*)d_in[2];
    const float* Wk = (const float*)d_in[3];
    const float* bk = (const float*)d_in[4];
    const float* Wv = (const float*)d_in[5];
    const float* bv = (const float*)d_in[6];
    const float* Wo = (const float*)d_in[7];
    const float* bo = (const float*)d_in[8];
    float* out = (float*)d_out;

    char* ws = (char*)d_ws;
    constexpr size_t SZ_ME = (size_t)Mq * Eq * 2;        // 8 MB
    u16*   Qb  = (u16*)  (ws + 0 * SZ_ME);
    u16*   Kb  = (u16*)  (ws + 1 * SZ_ME);
    u16*   KbT = (u16*)  (ws + 2 * SZ_ME);
    u16*   VbT = (u16*)  (ws + 3 * SZ_ME);
    u16*   Ob  = (u16*)  (ws + 4 * SZ_ME);
    float* KVT = (float*)(ws + 5 * SZ_ME);               // 16 MB f32
    u16*   STb = (u16*)  (ws + 5 * SZ_ME + (size_t)BH * NC * 4096 * 4);
    u16*   Xb  = (u16*)  (ws + 6 * SZ_ME + (size_t)BH * NC * 4096 * 4);
    u16*   Wb0 = (u16*)  (ws + 7 * SZ_ME + (size_t)BH * NC * 4096 * 4);
    u16* Wqkvb = Wb0;                                    // [Wq|Wk|Wv] as [3072][1024]
    u16* Wob   = Wb0 + (size_t)3 * Eq * Eq;

    // 1) bf16 conversions
    {
        int n4x = Mq * Eq / 4;
        cvt_kernel<<<dim3((n4x + 255) / 256), dim3(256), 0, stream>>>(x, Xb, n4x);
        int n4w = Eq * Eq / 4;
        cvt4_kernel<<<dim3((n4w + 255) / 256, 4), dim3(256), 0, stream>>>(
            Wq, Wk, Wv, Wo, Wb0, n4w);
    }

    // 2) fused QKV projection: 256x256 tiles, 8-wave phased schedule
    qkv_kernel<<<dim3(12, 16), dim3(512), 0, stream>>>(
        Xb, Wqkvb, bq, bk, bv, Qb, Kb, KbT, VbT);

    // 3) attention
    chunk_kv_kernel<<<dim3(BH * NC), dim3(64), 0, stream>>>(KbT, VbT, KVT);
    scan_kernel<<<dim3(BH * 16), dim3(256), 0, stream>>>(KVT, STb);
    attn_kernel<<<dim3(BH * NC), dim3(64), 0, stream>>>(Qb, Kb, VbT, STb, Ob);

    // 4) output projection (M=4096, N=1024), BM=64 -> 512 blocks (2/CU)
    oproj_kernel<<<dim3(8, 64), dim3(256), 0, stream>>>(Ob, Wob, bo, out);
}

// Round 5
// 92.230 us; speedup vs baseline: 1.1221x; 1.1221x over previous
//
#include <hip/hip_runtime.h>
#include <hip/hip_bf16.h>
#include <cmath>

typedef unsigned short u16;
typedef __bf16 bf16x8 __attribute__((ext_vector_type(8)));
typedef float  f32x4  __attribute__((ext_vector_type(4)));
typedef float  f4     __attribute__((ext_vector_type(4)));
typedef u16    us4    __attribute__((ext_vector_type(4)));

#define DEVFN __device__ __forceinline__

static constexpr int Bq = 2, Nq = 2048, Eq = 1024;
static constexpr int Mq = Bq * Nq;        // 4096 tokens
static constexpr int CHK = 64;            // attention chunk
static constexpr int NC  = Nq / CHK;      // 32 chunks
static constexpr int BH  = Bq * 16;       // 32

DEVFN u16 f2b(float f) {                  // f32 -> bf16 (RNE), finite inputs
    union { float f; unsigned int u; } x; x.f = f;
    unsigned int r = x.u + 0x7fffu + ((x.u >> 16) & 1u);
    return (u16)(r >> 16);
}
DEVFN float b2f(u16 v) {
    union { unsigned int u; float f; } x; x.u = ((unsigned int)v) << 16; return x.f;
}

DEVFN void gl_lds16(const u16* g, u16* l) {  // async 16B global->LDS (dest: wave base + lane*16)
    __builtin_amdgcn_global_load_lds(
        (const __attribute__((address_space(1))) unsigned int*)(g),
        (__attribute__((address_space(3))) unsigned int*)(l),
        16, 0, 0);
}

// ---------------- all f32 -> bf16 converts in ONE launch ----------------
// blocks [0,4096): x (4M elems); [4096,8192): weights Wq|Wk|Wv|Wo (1M each)
__global__ __launch_bounds__(256)
void cvt_all_kernel(const float* __restrict__ x,
                    const float* __restrict__ w0, const float* __restrict__ w1,
                    const float* __restrict__ w2, const float* __restrict__ w3,
                    u16* __restrict__ Xb, u16* __restrict__ Wb)
{
    const int blk = blockIdx.x;
    const float* s; u16* d; int i;
    if (blk < 4096) {
        i = blk * 256 + threadIdx.x;  s = x;  d = Xb;
    } else {
        const int wsel = (blk - 4096) >> 10;
        i = ((blk - 4096) & 1023) * 256 + threadIdx.x;
        s = (wsel == 0) ? w0 : (wsel == 1) ? w1 : (wsel == 2) ? w2 : w3;
        d = Wb + (size_t)wsel * (Eq * Eq);
    }
    f4 v = *reinterpret_cast<const f4*>(&s[(size_t)i * 4]);
    us4 p; p[0] = f2b(v[0]); p[1] = f2b(v[1]); p[2] = f2b(v[2]); p[3] = f2b(v[3]);
    *reinterpret_cast<us4*>(&d[(size_t)i * 4]) = p;
}

// ======== ring GEMM: BMx128 tile, BK=32, 3-buffer LDS ring, counted vmcnt ========
// out[m][n] = act(sum_k X[m][k]*W[n][k] + bias[n])
// MODE 0: fused QKV, BM=128, N=3072 (seg 0=Q elu+1, 1=K elu+1 ->Kb+KbT, 2=V ->VbT)
// MODE 1: O-projection, BM=64, N=1024, f32 output.
// Per iter t: stage tile t+2 into buf[(t+2)%3]; ds_read+MFMA on buf[t%3];
// s_waitcnt vmcnt(LOADS) (tile t+1 landed, t+2 in flight); raw s_barrier.
template<int MODE>
__global__ __launch_bounds__(256)
void gemm_ring(const u16* __restrict__ X, const u16* __restrict__ W,
               const float* __restrict__ b0, const float* __restrict__ b1,
               const float* __restrict__ b2,
               u16* __restrict__ Qb, u16* __restrict__ Kb, u16* __restrict__ KbT,
               u16* __restrict__ VbT, float* __restrict__ outF)
{
    constexpr int BM  = (MODE == 0) ? 128 : 64;
    constexpr int MI  = BM / 32;            // A-frags per wave
    constexpr int AI  = BM / 64;            // A staging rounds (16B/thread each)
    constexpr int BUF = BM * 32 + 4096;     // u16 per ring buffer (A | B)
    constexpr int NT  = 32;                 // K tiles (1024/32)
    __shared__ u16 lds[3 * BUF];            // 48KB (MODE0) / 36KB (MODE1)

    const int tid = threadIdx.x, wid = tid >> 6, lane = tid & 63;
    // XCD-bijective block swizzle (grid % 8 == 0 in both modes)
    const int fid = (MODE == 0) ? ((blockIdx.x & 7) * 96 + (blockIdx.x >> 3))
                                : ((blockIdx.x & 7) * 64 + (blockIdx.x >> 3));
    const int bx  = (MODE == 0) ? (fid % 24) : (fid & 7);
    const int by  = (MODE == 0) ? (fid / 24) : (fid >> 3);
    const int m0  = by * BM, n0 = bx * 128;
    const int wr  = (wid >> 1) * (BM / 2), wc = (wid & 1) * 64;
    const int fr  = lane & 15, fq = lane >> 4;

    // staging: thread covers 16B; slot = it*256+tid; row = slot>>2; 4 slots/row.
    // source slot is XOR-swizzled (involution), LDS dest linear.
    const int srow0 = tid >> 2;                       // + it*64 per round
    const int scol  = ((tid & 3) ^ (srow0 & 3)) * 8;  // swizzled global 16B slot
    const u16* gA = X + (size_t)(m0 + srow0) * 1024 + scol;
    const u16* gB = W + (size_t)(n0 + srow0) * 1024 + scol;
    const int dA = wid * 512;                         // + buf + it*2048 (wave-uniform)
    const int dB = BM * 32 + wid * 512;

    // fragment read offsets (u16), same XOR on read side
    const int fsw = (fq ^ (fr & 3)) << 3;
    int aoff[MI], boff[4];
#pragma unroll
    for (int mi = 0; mi < MI; ++mi) aoff[mi] = (wr + mi * 16 + fr) * 32 + fsw;
#pragma unroll
    for (int ni = 0; ni < 4; ++ni)  boff[ni] = BM * 32 + (wc + ni * 16 + fr) * 32 + fsw;

#define STAGE(kt, bsel) do {                                                   \
        const int _k = (kt) * 32;                                              \
        u16* _b = lds + (bsel) * BUF;                                          \
        _Pragma("unroll")                                                      \
        for (int it = 0; it < AI; ++it)                                        \
            gl_lds16(gA + _k + (size_t)it * 64 * 1024, _b + dA + it * 2048);   \
        _Pragma("unroll")                                                      \
        for (int it = 0; it < 2; ++it)                                         \
            gl_lds16(gB + _k + (size_t)it * 64 * 1024, _b + dB + it * 2048);   \
    } while (0)

    // prologue: tiles 0,1; wait tile0 (tile1's LOADS still in flight)
    STAGE(0, 0);
    STAGE(1, 1);
    if (MODE == 0) asm volatile("s_waitcnt vmcnt(4)" ::: "memory");
    else           asm volatile("s_waitcnt vmcnt(3)" ::: "memory");
    __builtin_amdgcn_s_barrier();
    __builtin_amdgcn_sched_barrier(0);

    f32x4 acc[MI][4] = {};
    int cb = 0, sb = 2;                      // current / stage buffer selectors

    for (int t = 0; t < NT; ++t) {
        if (t + 2 < NT) STAGE(t + 2, sb);
        const u16* buf = lds + cb * BUF;
        bf16x8 af[MI], bfv[4];
#pragma unroll
        for (int mi = 0; mi < MI; ++mi)
            af[mi] = *reinterpret_cast<const bf16x8*>(&buf[aoff[mi]]);
#pragma unroll
        for (int ni = 0; ni < 4; ++ni)
            bfv[ni] = *reinterpret_cast<const bf16x8*>(&buf[boff[ni]]);
#pragma unroll
        for (int mi = 0; mi < MI; ++mi)
#pragma unroll
            for (int ni = 0; ni < 4; ++ni)
                acc[mi][ni] = __builtin_amdgcn_mfma_f32_16x16x32_bf16(
                    af[mi], bfv[ni], acc[mi][ni], 0, 0, 0);
        // tile boundary: t+1 must have landed; keep t+2's loads in flight
        if (t < NT - 2) {
            if (MODE == 0) asm volatile("s_waitcnt vmcnt(4)" ::: "memory");
            else           asm volatile("s_waitcnt vmcnt(3)" ::: "memory");
        } else if (t == NT - 2) {
            asm volatile("s_waitcnt vmcnt(0)" ::: "memory");
        }
        __builtin_amdgcn_s_barrier();
        __builtin_amdgcn_sched_barrier(0);
        cb = (cb == 2) ? 0 : cb + 1;
        sb = (sb == 2) ? 0 : sb + 1;
    }
#undef STAGE

    if (MODE == 0) {
        const int seg = n0 >> 10;                          // 0=q 1=k 2=v
        const float* bp = (seg == 0) ? b0 : (seg == 1) ? b1 : b2;
#pragma unroll
        for (int mi = 0; mi < MI; ++mi)
#pragma unroll
            for (int ni = 0; ni < 4; ++ni) {
                const int nl    = (n0 & 1023) + wc + ni * 16 + fr;
                const int mbase = m0 + wr + mi * 16 + fq * 4;
                const float bn  = bp[nl];
                float vr[4];
#pragma unroll
                for (int r = 0; r < 4; ++r) {
                    float v = acc[mi][ni][r] + bn;
                    if (seg < 2) v = (v > 0.f) ? (v + 1.f) : __expf(v);  // elu+1
                    vr[r] = v;
                }
                if (seg == 0) {
#pragma unroll
                    for (int r = 0; r < 4; ++r)
                        Qb[(size_t)(mbase + r) * 1024 + nl] = f2b(vr[r]);
                } else {
                    us4 pk;
#pragma unroll
                    for (int r = 0; r < 4; ++r) pk[r] = f2b(vr[r]);
                    const int bb = mbase >> 11, nt = mbase & 2047;
                    const int hh = nl >> 6,     dd = nl & 63;
                    u16* T = (seg == 1) ? KbT : VbT;
                    *reinterpret_cast<us4*>(
                        &T[((size_t)(bb * 16 + hh) * 64 + dd) * 2048 + nt]) = pk;
                    if (seg == 1) {
#pragma unroll
                        for (int r = 0; r < 4; ++r)
                            Kb[(size_t)(mbase + r) * 1024 + nl] = f2b(vr[r]);
                    }
                }
            }
    } else {
#pragma unroll
        for (int mi = 0; mi < MI; ++mi)
#pragma unroll
            for (int ni = 0; ni < 4; ++ni) {
                const int n     = n0 + wc + ni * 16 + fr;
                const int mbase = m0 + wr + mi * 16 + fq * 4;
                const float bn  = b0[n];
#pragma unroll
                for (int r = 0; r < 4; ++r)
                    outF[(size_t)(mbase + r) * 1024 + n] = acc[mi][ni][r] + bn;
            }
    }
}

// ---------------- per-chunk KV^T = v^T @ k: KVT[de][dk], bf16 out ----------------
__global__ __launch_bounds__(64)
void chunk_kv_kernel(const u16* __restrict__ KbT, const u16* __restrict__ VbT,
                     u16* __restrict__ KVT)
{
    const int blk = blockIdx.x;          // bh*NC + c
    const int bh = blk >> 5, c = blk & 31;
    const int lane = threadIdx.x;
    const int fr = lane & 15, fq = lane >> 4, fk = fq * 8;
    const u16* kt = KbT + (size_t)bh * 64 * 2048;
    const u16* vt = VbT + (size_t)bh * 64 * 2048;

    bf16x8 a[4][2], b[4][2];             // a = V rows (de), b = K rows (dk)
#pragma unroll
    for (int mi = 0; mi < 4; ++mi)
#pragma unroll
        for (int kh = 0; kh < 2; ++kh)
            a[mi][kh] = *reinterpret_cast<const bf16x8*>(
                &vt[(size_t)(mi * 16 + fr) * 2048 + c * 64 + kh * 32 + fk]);
#pragma unroll
    for (int ni = 0; ni < 4; ++ni)
#pragma unroll
        for (int kh = 0; kh < 2; ++kh)
            b[ni][kh] = *reinterpret_cast<const bf16x8*>(
                &kt[(size_t)(ni * 16 + fr) * 2048 + c * 64 + kh * 32 + fk]);

    f32x4 acc[4][4] = {};
#pragma unroll
    for (int mi = 0; mi < 4; ++mi)
#pragma unroll
        for (int ni = 0; ni < 4; ++ni)
#pragma unroll
            for (int kh = 0; kh < 2; ++kh)
                acc[mi][ni] = __builtin_amdgcn_mfma_f32_16x16x32_bf16(
                    a[mi][kh], b[ni][kh], acc[mi][ni], 0, 0, 0);

    u16* out = KVT + (size_t)blk * 4096;   // [de][dk] bf16
#pragma unroll
    for (int mi = 0; mi < 4; ++mi)
#pragma unroll
        for (int ni = 0; ni < 4; ++ni)
#pragma unroll
            for (int r = 0; r < 4; ++r)
                out[(mi * 16 + fq * 4 + r) * 64 + ni * 16 + fr] = f2b(acc[mi][ni][r]);
}

// ---------------- elementwise exclusive scan over chunks (bf16 in, bf16 out) ----------------
__global__ __launch_bounds__(256)
void scan_kernel(const u16* __restrict__ KVT, u16* __restrict__ STb)
{
    const int bh = blockIdx.x >> 4, sl = blockIdx.x & 15;
    const int el = sl * 256 + threadIdx.x;              // element of [de][dk]
    const u16* src = KVT + (size_t)bh * NC * 4096 + el;
    u16*      dst  = STb + (size_t)bh * NC * 4096 + el;
    float run = 0.f;
#pragma unroll 4
    for (int c = 0; c < NC; ++c) {
        dst[(size_t)c * 4096] = f2b(run);               // exclusive prefix
        run += b2f(src[(size_t)c * 4096]);
    }
}

// ---------------- per-chunk attention output ----------------
__global__ __launch_bounds__(64)
void attn_kernel(const u16* __restrict__ Qb, const u16* __restrict__ Kb,
                 const u16* __restrict__ VbT, const u16* __restrict__ STb,
                 u16* __restrict__ Ob)
{
    __shared__ u16 P[64 * 72];   // stride 72 u16 = 144B: 16B-aligned, 2-way banks
    const int blk = blockIdx.x;
    const int bh = blk >> 5, c = blk & 31;
    const int b = bh >> 4, h = bh & 15;
    const int lane = threadIdx.x;
    const int fr = lane & 15, fq = lane >> 4, fk = fq * 8;
    const int tok0 = b * 2048 + c * 64;

    bf16x8 qa[4][2];
#pragma unroll
    for (int mi = 0; mi < 4; ++mi)
#pragma unroll
        for (int kh = 0; kh < 2; ++kh)
            qa[mi][kh] = *reinterpret_cast<const bf16x8*>(
                &Qb[(size_t)(tok0 + mi * 16 + fr) * 1024 + h * 64 + kh * 32 + fk]);

    // P = causal-mask(q @ k^T) -> LDS bf16
    {
        bf16x8 kb[4][2];
#pragma unroll
        for (int si = 0; si < 4; ++si)
#pragma unroll
            for (int kh = 0; kh < 2; ++kh)
                kb[si][kh] = *reinterpret_cast<const bf16x8*>(
                    &Kb[(size_t)(tok0 + si * 16 + fr) * 1024 + h * 64 + kh * 32 + fk]);
        f32x4 p[4][4] = {};
#pragma unroll
        for (int mi = 0; mi < 4; ++mi)
#pragma unroll
            for (int si = 0; si < 4; ++si)
#pragma unroll
                for (int kh = 0; kh < 2; ++kh)
                    p[mi][si] = __builtin_amdgcn_mfma_f32_16x16x32_bf16(
                        qa[mi][kh], kb[si][kh], p[mi][si], 0, 0, 0);
#pragma unroll
        for (int mi = 0; mi < 4; ++mi)
#pragma unroll
            for (int si = 0; si < 4; ++si)
#pragma unroll
                for (int r = 0; r < 4; ++r) {
                    int t = mi * 16 + fq * 4 + r;
                    int s = si * 16 + fr;
                    float v = (s <= t) ? p[mi][si][r] : 0.0f;
                    P[t * 72 + s] = f2b(v);
                }
    }
    __syncthreads();

    f32x4 acc[4][4] = {};
    // acc = q @ ST   (STb[de][dk], dk-contiguous)
    {
        const u16* st = STb + (size_t)blk * 4096;
        bf16x8 sb[4][2];
#pragma unroll
        for (int ni = 0; ni < 4; ++ni)
#pragma unroll
            for (int kh = 0; kh < 2; ++kh)
                sb[ni][kh] = *reinterpret_cast<const bf16x8*>(
                    &st[(ni * 16 + fr) * 64 + kh * 32 + fk]);
#pragma unroll
        for (int mi = 0; mi < 4; ++mi)
#pragma unroll
            for (int ni = 0; ni < 4; ++ni)
#pragma unroll
                for (int kh = 0; kh < 2; ++kh)
                    acc[mi][ni] = __builtin_amdgcn_mfma_f32_16x16x32_bf16(
                        qa[mi][kh], sb[ni][kh], acc[mi][ni], 0, 0, 0);
    }
    // acc += P @ v
    {
        const u16* vt = VbT + (size_t)bh * 64 * 2048;
#pragma unroll
        for (int sh = 0; sh < 2; ++sh) {
            bf16x8 pa[4], vb[4];
#pragma unroll
            for (int mi = 0; mi < 4; ++mi)
                pa[mi] = *reinterpret_cast<const bf16x8*>(
                    &P[(mi * 16 + fr) * 72 + sh * 32 + fk]);
#pragma unroll
            for (int ni = 0; ni < 4; ++ni)
                vb[ni] = *reinterpret_cast<const bf16x8*>(
                    &vt[(size_t)(ni * 16 + fr) * 2048 + c * 64 + sh * 32 + fk]);
#pragma unroll
            for (int mi = 0; mi < 4; ++mi)
#pragma unroll
                for (int ni = 0; ni < 4; ++ni)
                    acc[mi][ni] = __builtin_amdgcn_mfma_f32_16x16x32_bf16(
                        pa[mi], vb[ni], acc[mi][ni], 0, 0, 0);
        }
    }
    // write token-major bf16 O
#pragma unroll
    for (int mi = 0; mi < 4; ++mi)
#pragma unroll
        for (int ni = 0; ni < 4; ++ni)
#pragma unroll
            for (int r = 0; r < 4; ++r) {
                int t = tok0 + mi * 16 + fq * 4 + r;
                int n = h * 64 + ni * 16 + fr;
                Ob[(size_t)t * 1024 + n] = f2b(acc[mi][ni][r]);
            }
}

extern "C" void kernel_launch(void* const* d_in, const int* in_sizes, int n_in,
                              void* d_out, int out_size, void* d_ws, size_t ws_size,
                              hipStream_t stream)
{
    (void)in_sizes; (void)n_in; (void)out_size; (void)ws_size;
    const float* x  = (const float*)d_in[0];
    const float* Wq = (const float*)d_in[1];
    const float* bq = (const float*)d_in[2];
    const float* Wk = (const float*)d_in[3];
    const float* bk = (const float*)d_in[4];
    const float* Wv = (const float*)d_in[5];
    const float* bv = (const float*)d_in[6];
    const float* Wo = (const float*)d_in[7];
    const float* bo = (const float*)d_in[8];
    float* out = (float*)d_out;

    char* ws = (char*)d_ws;
    constexpr size_t SZ_ME = (size_t)Mq * Eq * 2;        // 8 MB
    u16*   Qb  = (u16*)  (ws + 0 * SZ_ME);
    u16*   Kb  = (u16*)  (ws + 1 * SZ_ME);
    u16*   KbT = (u16*)  (ws + 2 * SZ_ME);
    u16*   VbT = (u16*)  (ws + 3 * SZ_ME);
    u16*   Ob  = (u16*)  (ws + 4 * SZ_ME);
    u16*   KVT = (u16*)  (ws + 5 * SZ_ME);               // 8 MB bf16
    u16*   STb = (u16*)  (ws + 6 * SZ_ME);
    u16*   Xb  = (u16*)  (ws + 7 * SZ_ME);
    u16*   Wb0 = (u16*)  (ws + 8 * SZ_ME);               // [Wq|Wk|Wv|Wo] bf16
    u16* Wqkvb = Wb0;
    u16* Wob   = Wb0 + (size_t)3 * Eq * Eq;

    // 1) all bf16 conversions, one launch
    cvt_all_kernel<<<dim3(8192), dim3(256), 0, stream>>>(x, Wq, Wk, Wv, Wo, Xb, Wb0);

    // 2) fused QKV projection (M=4096, N=3072): ring GEMM, 768 blocks (3/CU)
    gemm_ring<0><<<dim3(768), dim3(256), 0, stream>>>(
        Xb, Wqkvb, bq, bk, bv, Qb, Kb, KbT, VbT, nullptr);

    // 3) attention
    chunk_kv_kernel<<<dim3(BH * NC), dim3(64), 0, stream>>>(KbT, VbT, KVT);
    scan_kernel<<<dim3(BH * 16), dim3(256), 0, stream>>>(KVT, STb);
    attn_kernel<<<dim3(BH * NC), dim3(64), 0, stream>>>(Qb, Kb, VbT, STb, Ob);

    // 4) output projection (M=4096, N=1024): ring GEMM, 512 blocks
    gemm_ring<1><<<dim3(512), dim3(256), 0, stream>>>(
        Ob, Wob, bo, nullptr, nullptr, nullptr, nullptr, nullptr, nullptr, out);
}